// Round 15
// baseline (184.764 us; speedup 1.0000x reference)
//
#include <hip/hip_runtime.h>

#define NB 32768
#define NF 256
#define H1 16
#define H2 8
#define ROWS_PER_BLOCK 1024
#define ITERS (ROWS_PER_BLOCK / 64)   // 16 (one row per lane per iter)
#define FPB 4                         // features (waves) per block
#define NT (FPB * 64)                 // 256 threads

typedef float v2f __attribute__((ext_vector_type(2)));

__device__ __forceinline__ float elu_f(float v) {
    return v > 0.0f ? v : (__expf(v) - 1.0f);
}
// force a wave-uniform float into an SGPR
__device__ __forceinline__ float rfl(float v) {
    return __int_as_float(__builtin_amdgcn_readfirstlane(__float_as_int(v)));
}

// R14 skeleton (wave-per-feature, W2 rows0-7 SGPR + rows8-15 LDS, cross-row
// h1 pipeline, no in-loop barriers) with two additions:
//  1) FUSED y: per row-iter each wave atomically adds wv*z (+bias once) into
//     y[row] -> y_kernel eliminated (kernel_launch memsets y first).
//  2) PACKED L2 on the LDS path: acc held as v2f[4]; 64 scalar v_fma -> 32
//     v_pk_fma_f32 per row. SGPR path stays scalar (fma's free SGPR operand).
// Register demand ~65 vs budget 102 at (256,5): cushion preserved (R13's
// spill was at cushion ~10; R14 proved this skeleton runs clean).
__global__ __launch_bounds__(NT, 5)
void z_kernel(const float* __restrict__ x,  const float* __restrict__ W1,
              const float* __restrict__ b1, const float* __restrict__ W2,
              const float* __restrict__ b2, const float* __restrict__ W3,
              const float* __restrict__ b3, const float* __restrict__ theta,
              const float* __restrict__ bias,
              float* __restrict__ y_out, float* __restrict__ w_out,
              float* __restrict__ z_out) {
    const int wave = threadIdx.x >> 6;
    const int lane = threadIdx.x & 63;
    const int f    = blockIdx.y * FPB + wave;
    const int rowBase = blockIdx.x * ROWS_PER_BLOCK;

    __shared__ float lds_w2[FPB][64];        // W2 rows 8..15 per feature

    // ---- stage W2 rows 8..15 into LDS (16 lanes x float4) ----
    if (lane < 16) {
        const float4 v = reinterpret_cast<const float4*>(W2 + f * H1 * H2 + 64)[lane];
        reinterpret_cast<float4*>(lds_w2[wave])[lane] = v;
    }

    // ---- W2 rows 0..7 -> SGPR ----
    float s_w2[8 * H2];
    {
        const float4* p = reinterpret_cast<const float4*>(W2 + f * H1 * H2);
        #pragma unroll
        for (int i = 0; i < 16; ++i) {
            float4 v = p[i];
            s_w2[4*i]   = rfl(v.x); s_w2[4*i+1] = rfl(v.y);
            s_w2[4*i+2] = rfl(v.z); s_w2[4*i+3] = rfl(v.w);
        }
    }
    // ---- W1 -> per-lane VGPR, b1 -> SGPR ----
    float w1v[H1], s_b1[H1];
    {
        const float4* pw = reinterpret_cast<const float4*>(W1 + f * H1);
        const float4* pb = reinterpret_cast<const float4*>(b1 + f * H1);
        #pragma unroll
        for (int i = 0; i < 4; ++i) {
            float4 v = pw[i];
            w1v[4*i] = v.x; w1v[4*i+1] = v.y; w1v[4*i+2] = v.z; w1v[4*i+3] = v.w;
        }
        #pragma unroll
        for (int i = 0; i < 4; ++i) {
            float4 v = pb[i];
            s_b1[4*i]   = rfl(v.x); s_b1[4*i+1] = rfl(v.y);
            s_b1[4*i+2] = rfl(v.z); s_b1[4*i+3] = rfl(v.w);
        }
    }
    // ---- b2 -> per-lane VGPR pairs; W3, b3 -> SGPR ----
    v2f b2p[4];
    {
        const float4* p = reinterpret_cast<const float4*>(b2 + f * H2);
        float4 v0 = p[0], v1 = p[1];
        b2p[0] = (v2f){v0.x, v0.y}; b2p[1] = (v2f){v0.z, v0.w};
        b2p[2] = (v2f){v1.x, v1.y}; b2p[3] = (v2f){v1.z, v1.w};
    }
    float s_w3[H2];
    {
        const float4* p = reinterpret_cast<const float4*>(W3 + f * H2);
        float4 v0 = p[0], v1 = p[1];
        s_w3[0]=rfl(v0.x); s_w3[1]=rfl(v0.y); s_w3[2]=rfl(v0.z); s_w3[3]=rfl(v0.w);
        s_w3[4]=rfl(v1.x); s_w3[5]=rfl(v1.y); s_w3[6]=rfl(v1.z); s_w3[7]=rfl(v1.w);
    }
    const float s_b3 = rfl(b3[f]);
    // softplus weight for fused y; bias added once per row (by block y==0, wave 0)
    const float wv = rfl(logf(1.0f + __expf(theta[f])));
    const float ybias = (blockIdx.y == 0 && wave == 0) ? bias[0] : 0.0f;

    if (blockIdx.x == 0 && lane == 0) w_out[f] = wv;

    __syncthreads();                          // LDS W2 ready

    const float* wbase = lds_w2[wave];

    // cross-row pipeline: h1c holds row `it`'s ELUs, refilled with row it+1
    const int off0 = (rowBase + lane) * NF + f;
    float h1c[H1];
    {
        const float xv = x[off0];             // row 0
        #pragma unroll
        for (int h = 0; h < H1; ++h)
            h1c[h] = elu_f(fmaf(xv, w1v[h], s_b1[h]));
    }
    float xn  = x[off0 + 64 * NF];            // row 1 (ITERS >= 2)
    int off = off0;

    #pragma unroll 1
    for (int it = 0; it < ITERS; ++it) {
        // prefetch x for row it+2
        const int off2 = off + 2 * 64 * NF;
        const float xnn = x[(it + 2 < ITERS) ? off2 : off];

        v2f accp[4];
        #pragma unroll
        for (int j = 0; j < 4; ++j) accp[j] = b2p[j];

        // ---- W2 rows 0..7: SGPR path (scalar fma, free SGPR operand) ----
        #pragma unroll
        for (int h = 0; h < 8; ++h) {
            const float hc = h1c[h];
            h1c[h] = elu_f(fmaf(xn, w1v[h], s_b1[h]));
            accp[0].x = fmaf(hc, s_w2[h*H2 + 0], accp[0].x);
            accp[0].y = fmaf(hc, s_w2[h*H2 + 1], accp[0].y);
            accp[1].x = fmaf(hc, s_w2[h*H2 + 2], accp[1].x);
            accp[1].y = fmaf(hc, s_w2[h*H2 + 3], accp[1].y);
            accp[2].x = fmaf(hc, s_w2[h*H2 + 4], accp[2].x);
            accp[2].y = fmaf(hc, s_w2[h*H2 + 5], accp[2].y);
            accp[3].x = fmaf(hc, s_w2[h*H2 + 6], accp[3].x);
            accp[3].y = fmaf(hc, s_w2[h*H2 + 7], accp[3].y);
        }

        // ---- W2 rows 8..15: LDS path, packed v_pk_fma_f32 ----
        int dsoff = 0;                        // block LICM hoisting
        asm volatile("" : "+v"(dsoff));
        const float4* wp = reinterpret_cast<const float4*>(wbase + dsoff);
        #pragma unroll
        for (int h = 0; h < 8; ++h) {
            const float4 wlo = wp[2 * h];
            const float4 whi = wp[2 * h + 1];
            const float hc = h1c[8 + h];
            h1c[8 + h] = elu_f(fmaf(xn, w1v[8 + h], s_b1[8 + h]));
            const v2f hcp = (v2f){hc, hc};
            accp[0] += (v2f){wlo.x, wlo.y} * hcp;
            accp[1] += (v2f){wlo.z, wlo.w} * hcp;
            accp[2] += (v2f){whi.x, whi.y} * hcp;
            accp[3] += (v2f){whi.z, whi.w} * hcp;
        }

        float z = s_b3;
        #pragma unroll
        for (int j = 0; j < 4; ++j) {
            z = fmaf(elu_f(accp[j].x), s_w3[2*j],     z);
            z = fmaf(elu_f(accp[j].y), s_w3[2*j + 1], z);
        }

        z_out[off] = z;                       // row it
        // fused y: one atomic per (row, feature)
        atomicAdd(y_out + (rowBase + it * 64 + lane), fmaf(wv, z, ybias));

        off += 64 * NF; xn = xnn;
    }
}

extern "C" void kernel_launch(void* const* d_in, const int* in_sizes, int n_in,
                              void* d_out, int out_size, void* d_ws, size_t ws_size,
                              hipStream_t stream) {
    const float* x     = (const float*)d_in[0];
    const float* W1    = (const float*)d_in[1];
    const float* b1    = (const float*)d_in[2];
    const float* W2    = (const float*)d_in[3];
    const float* b2    = (const float*)d_in[4];
    const float* W3    = (const float*)d_in[5];
    const float* b3    = (const float*)d_in[6];
    const float* theta = (const float*)d_in[7];
    const float* bias  = (const float*)d_in[8];

    float* y_out = (float*)d_out;                  // [32768]
    float* w_out = y_out + NB;                     // [256]
    float* z_out = w_out + NF;                     // [32768*256]

    hipMemsetAsync(y_out, 0, NB * sizeof(float), stream);  // y accumulated via atomics

    dim3 grid1(NB / ROWS_PER_BLOCK, NF / FPB);     // 32 x 64
    z_kernel<<<grid1, NT, 0, stream>>>(x, W1, b1, W2, b2, W3, b3, theta, bias,
                                       y_out, w_out, z_out);
}

// Round 16
// 165.729 us; speedup vs baseline: 1.1149x; 1.1149x over previous
//
#include <hip/hip_runtime.h>

#define NB 32768
#define NF 256
#define H1 16
#define H2 8
#define ROWS_PER_BLOCK 1024
#define ITERS (ROWS_PER_BLOCK / 64)   // 16 (one row per lane per iter)
#define FPB 4                         // features (waves) per block
#define NT (FPB * 64)                 // 256 threads

typedef float v2f __attribute__((ext_vector_type(2)));

__device__ __forceinline__ float elu_f(float v) {
    return v > 0.0f ? v : (__expf(v) - 1.0f);
}
// force a wave-uniform float into an SGPR
__device__ __forceinline__ float rfl(float v) {
    return __int_as_float(__builtin_amdgcn_readfirstlane(__float_as_int(v)));
}

// R14 skeleton EXACTLY (wave-per-feature, W2 rows0-7 SGPR + rows8-15 LDS,
// cross-row h1 pipeline, scattered x/z, separate y_kernel) with ONE change:
// the LDS-path L2 accumulation is held as v2f[4] and uses v_pk_fma_f32
// (64 scalar fma -> 32 pk_fma per row). R15 bundled this with fused-y
// atomics (which regressed 82->106us); this round isolates the pk effect.
__global__ __launch_bounds__(NT, 5)
void z_kernel(const float* __restrict__ x,  const float* __restrict__ W1,
              const float* __restrict__ b1, const float* __restrict__ W2,
              const float* __restrict__ b2, const float* __restrict__ W3,
              const float* __restrict__ b3, float* __restrict__ z_out) {
    const int wave = threadIdx.x >> 6;
    const int lane = threadIdx.x & 63;
    const int f    = blockIdx.y * FPB + wave;
    const int rowBase = blockIdx.x * ROWS_PER_BLOCK;

    __shared__ float lds_w2[FPB][64];        // W2 rows 8..15 per feature

    // ---- stage W2 rows 8..15 into LDS (16 lanes x float4) ----
    if (lane < 16) {
        const float4 v = reinterpret_cast<const float4*>(W2 + f * H1 * H2 + 64)[lane];
        reinterpret_cast<float4*>(lds_w2[wave])[lane] = v;
    }

    // ---- W2 rows 0..7 -> SGPR ----
    float s_w2[8 * H2];
    {
        const float4* p = reinterpret_cast<const float4*>(W2 + f * H1 * H2);
        #pragma unroll
        for (int i = 0; i < 16; ++i) {
            float4 v = p[i];
            s_w2[4*i]   = rfl(v.x); s_w2[4*i+1] = rfl(v.y);
            s_w2[4*i+2] = rfl(v.z); s_w2[4*i+3] = rfl(v.w);
        }
    }
    // ---- W1 -> per-lane VGPR, b1 -> SGPR ----
    float w1v[H1], s_b1[H1];
    {
        const float4* pw = reinterpret_cast<const float4*>(W1 + f * H1);
        const float4* pb = reinterpret_cast<const float4*>(b1 + f * H1);
        #pragma unroll
        for (int i = 0; i < 4; ++i) {
            float4 v = pw[i];
            w1v[4*i] = v.x; w1v[4*i+1] = v.y; w1v[4*i+2] = v.z; w1v[4*i+3] = v.w;
        }
        #pragma unroll
        for (int i = 0; i < 4; ++i) {
            float4 v = pb[i];
            s_b1[4*i]   = rfl(v.x); s_b1[4*i+1] = rfl(v.y);
            s_b1[4*i+2] = rfl(v.z); s_b1[4*i+3] = rfl(v.w);
        }
    }
    // ---- b2 -> per-lane VGPR pairs; W3, b3 -> SGPR ----
    v2f b2p[4];
    {
        const float4* p = reinterpret_cast<const float4*>(b2 + f * H2);
        float4 v0 = p[0], v1 = p[1];
        b2p[0] = (v2f){v0.x, v0.y}; b2p[1] = (v2f){v0.z, v0.w};
        b2p[2] = (v2f){v1.x, v1.y}; b2p[3] = (v2f){v1.z, v1.w};
    }
    float s_w3[H2];
    {
        const float4* p = reinterpret_cast<const float4*>(W3 + f * H2);
        float4 v0 = p[0], v1 = p[1];
        s_w3[0]=rfl(v0.x); s_w3[1]=rfl(v0.y); s_w3[2]=rfl(v0.z); s_w3[3]=rfl(v0.w);
        s_w3[4]=rfl(v1.x); s_w3[5]=rfl(v1.y); s_w3[6]=rfl(v1.z); s_w3[7]=rfl(v1.w);
    }
    const float s_b3 = rfl(b3[f]);

    __syncthreads();                          // LDS W2 ready

    const float* wbase = lds_w2[wave];

    // cross-row pipeline: h1c holds row `it`'s ELUs, refilled with row it+1
    const int off0 = (rowBase + lane) * NF + f;
    float h1c[H1];
    {
        const float xv = x[off0];             // row 0
        #pragma unroll
        for (int h = 0; h < H1; ++h)
            h1c[h] = elu_f(fmaf(xv, w1v[h], s_b1[h]));
    }
    float xn  = x[off0 + 64 * NF];            // row 1 (ITERS >= 2)
    int off = off0;

    #pragma unroll 1
    for (int it = 0; it < ITERS; ++it) {
        // prefetch x for row it+2
        const int off2 = off + 2 * 64 * NF;
        const float xnn = x[(it + 2 < ITERS) ? off2 : off];

        v2f accp[4];
        #pragma unroll
        for (int j = 0; j < 4; ++j) accp[j] = b2p[j];

        // ---- W2 rows 0..7: SGPR path (scalar fma, free SGPR operand) ----
        #pragma unroll
        for (int h = 0; h < 8; ++h) {
            const float hc = h1c[h];
            h1c[h] = elu_f(fmaf(xn, w1v[h], s_b1[h]));
            accp[0].x = fmaf(hc, s_w2[h*H2 + 0], accp[0].x);
            accp[0].y = fmaf(hc, s_w2[h*H2 + 1], accp[0].y);
            accp[1].x = fmaf(hc, s_w2[h*H2 + 2], accp[1].x);
            accp[1].y = fmaf(hc, s_w2[h*H2 + 3], accp[1].y);
            accp[2].x = fmaf(hc, s_w2[h*H2 + 4], accp[2].x);
            accp[2].y = fmaf(hc, s_w2[h*H2 + 5], accp[2].y);
            accp[3].x = fmaf(hc, s_w2[h*H2 + 6], accp[3].x);
            accp[3].y = fmaf(hc, s_w2[h*H2 + 7], accp[3].y);
        }

        // ---- W2 rows 8..15: LDS path, packed v_pk_fma_f32 ----
        int dsoff = 0;                        // block LICM hoisting
        asm volatile("" : "+v"(dsoff));
        const float4* wp = reinterpret_cast<const float4*>(wbase + dsoff);
        #pragma unroll
        for (int h = 0; h < 8; ++h) {
            const float4 wlo = wp[2 * h];
            const float4 whi = wp[2 * h + 1];
            const float hc = h1c[8 + h];
            h1c[8 + h] = elu_f(fmaf(xn, w1v[8 + h], s_b1[8 + h]));
            const v2f hcp = (v2f){hc, hc};
            accp[0] += (v2f){wlo.x, wlo.y} * hcp;
            accp[1] += (v2f){wlo.z, wlo.w} * hcp;
            accp[2] += (v2f){whi.x, whi.y} * hcp;
            accp[3] += (v2f){whi.z, whi.w} * hcp;
        }

        float z = s_b3;
        #pragma unroll
        for (int j = 0; j < 4; ++j) {
            z = fmaf(elu_f(accp[j].x), s_w3[2*j],     z);
            z = fmaf(elu_f(accp[j].y), s_w3[2*j + 1], z);
        }

        z_out[off] = z;                       // row it
        off += 64 * NF; xn = xnn;
    }
}

// Memory-bound epilogue: w = softplus(theta); y[row] = dot(z[row,:], w) + bias.
#define NT2 256
#define ROWS2 64
__global__ __launch_bounds__(NT2, 4)
void y_kernel(const float* __restrict__ z, const float* __restrict__ theta,
              const float* __restrict__ bias, float* __restrict__ y_out,
              float* __restrict__ w_out) {
    __shared__ __align__(16) float wls[NF];
    const int tid = threadIdx.x;
    {
        const float th = theta[tid];
        const float w  = logf(1.0f + __expf(th));
        wls[tid] = w;
        if (blockIdx.x == 0) w_out[tid] = w;
    }
    __syncthreads();
    const int wave = tid >> 6, lane = tid & 63;
    const float4 w4 = reinterpret_cast<const float4*>(wls)[lane];
    const float biasv = bias[0];
    #pragma unroll 1
    for (int r = 0; r < ROWS2 / 4; ++r) {          // 16 rows per wave
        const int row = blockIdx.x * ROWS2 + wave * (ROWS2 / 4) + r;
        const float4 zv = reinterpret_cast<const float4*>(z + row * NF)[lane];
        float s = zv.x * w4.x + zv.y * w4.y + zv.z * w4.z + zv.w * w4.w;
        #pragma unroll
        for (int o = 32; o > 0; o >>= 1) s += __shfl_down(s, o, 64);
        if (lane == 0) y_out[row] = s + biasv;
    }
}

extern "C" void kernel_launch(void* const* d_in, const int* in_sizes, int n_in,
                              void* d_out, int out_size, void* d_ws, size_t ws_size,
                              hipStream_t stream) {
    const float* x     = (const float*)d_in[0];
    const float* W1    = (const float*)d_in[1];
    const float* b1    = (const float*)d_in[2];
    const float* W2    = (const float*)d_in[3];
    const float* b2    = (const float*)d_in[4];
    const float* W3    = (const float*)d_in[5];
    const float* b3    = (const float*)d_in[6];
    const float* theta = (const float*)d_in[7];
    const float* bias  = (const float*)d_in[8];

    float* y_out = (float*)d_out;                  // [32768]
    float* w_out = y_out + NB;                     // [256]
    float* z_out = w_out + NF;                     // [32768*256]

    dim3 grid1(NB / ROWS_PER_BLOCK, NF / FPB);     // 32 x 64
    z_kernel<<<grid1, NT, 0, stream>>>(x, W1, b1, W2, b2, W3, b3, z_out);
    y_kernel<<<NB / ROWS2, NT2, 0, stream>>>(z_out, theta, bias, y_out, w_out);
}

// Round 18
// 165.254 us; speedup vs baseline: 1.1181x; 1.0029x over previous
//
#include <hip/hip_runtime.h>

#define NB 32768
#define NF 256
#define H1 16
#define H2 8
#define ROWS_PER_BLOCK 1024
#define ITERS (ROWS_PER_BLOCK / 64)   // 16 (one row per lane per iter)
#define FPB 4                         // features (waves) per block
#define NT (FPB * 64)                 // 256 threads

__device__ __forceinline__ float elu_f(float v) {
    return v > 0.0f ? v : (__expf(v) - 1.0f);
}
// force a wave-uniform float into an SGPR
__device__ __forceinline__ float rfl(float v) {
    return __int_as_float(__builtin_amdgcn_readfirstlane(__float_as_int(v)));
}

// FINAL (R14): wave-per-feature; lanes = 64 rows. Params wave-uniform:
// W2 rows 0..7 + b1 + W3 + b3 in SGPRs (readfirstlane; v_fma takes one SGPR
// operand free), W2 rows 8..15 in LDS broadcast, w1/b2 per-lane VGPR.
// Cross-row h1 pipeline: iter `it` consumes h1c[] (row it, ready in regs)
// while overwriting each slot with row it+1's ELU. 2-deep x prefetch.
// Session plateau: six structures all issue ~53-55us of VALU at ~65% duty
// (z ~= 82us); occupancy/LDS/coalescing/pk_fma/atomic-fusion all neutral or
// negative. This variant is the best repeated median with clean counters
// (FETCH 17MB, WRITE 33MB, no spill, 0 bank conflicts).
__global__ __launch_bounds__(NT, 5)
void z_kernel(const float* __restrict__ x,  const float* __restrict__ W1,
              const float* __restrict__ b1, const float* __restrict__ W2,
              const float* __restrict__ b2, const float* __restrict__ W3,
              const float* __restrict__ b3, float* __restrict__ z_out) {
    const int wave = threadIdx.x >> 6;
    const int lane = threadIdx.x & 63;
    const int f    = blockIdx.y * FPB + wave;
    const int rowBase = blockIdx.x * ROWS_PER_BLOCK;

    __shared__ float lds_w2[FPB][64];        // W2 rows 8..15 per feature

    // ---- stage W2 rows 8..15 into LDS (16 lanes x float4) ----
    if (lane < 16) {
        const float4 v = reinterpret_cast<const float4*>(W2 + f * H1 * H2 + 64)[lane];
        reinterpret_cast<float4*>(lds_w2[wave])[lane] = v;
    }

    // ---- W2 rows 0..7 -> SGPR ----
    float s_w2[8 * H2];
    {
        const float4* p = reinterpret_cast<const float4*>(W2 + f * H1 * H2);
        #pragma unroll
        for (int i = 0; i < 16; ++i) {
            float4 v = p[i];
            s_w2[4*i]   = rfl(v.x); s_w2[4*i+1] = rfl(v.y);
            s_w2[4*i+2] = rfl(v.z); s_w2[4*i+3] = rfl(v.w);
        }
    }
    // ---- W1 -> per-lane VGPR, b1 -> SGPR ----
    float w1v[H1], s_b1[H1];
    {
        const float4* pw = reinterpret_cast<const float4*>(W1 + f * H1);
        const float4* pb = reinterpret_cast<const float4*>(b1 + f * H1);
        #pragma unroll
        for (int i = 0; i < 4; ++i) {
            float4 v = pw[i];
            w1v[4*i] = v.x; w1v[4*i+1] = v.y; w1v[4*i+2] = v.z; w1v[4*i+3] = v.w;
        }
        #pragma unroll
        for (int i = 0; i < 4; ++i) {
            float4 v = pb[i];
            s_b1[4*i]   = rfl(v.x); s_b1[4*i+1] = rfl(v.y);
            s_b1[4*i+2] = rfl(v.z); s_b1[4*i+3] = rfl(v.w);
        }
    }
    // ---- b2 -> per-lane VGPR; W3, b3 -> SGPR ----
    float b2v[H2];
    {
        const float4* p = reinterpret_cast<const float4*>(b2 + f * H2);
        float4 v0 = p[0], v1 = p[1];
        b2v[0]=v0.x; b2v[1]=v0.y; b2v[2]=v0.z; b2v[3]=v0.w;
        b2v[4]=v1.x; b2v[5]=v1.y; b2v[6]=v1.z; b2v[7]=v1.w;
    }
    float s_w3[H2];
    {
        const float4* p = reinterpret_cast<const float4*>(W3 + f * H2);
        float4 v0 = p[0], v1 = p[1];
        s_w3[0]=rfl(v0.x); s_w3[1]=rfl(v0.y); s_w3[2]=rfl(v0.z); s_w3[3]=rfl(v0.w);
        s_w3[4]=rfl(v1.x); s_w3[5]=rfl(v1.y); s_w3[6]=rfl(v1.z); s_w3[7]=rfl(v1.w);
    }
    const float s_b3 = rfl(b3[f]);

    __syncthreads();                          // LDS W2 ready

    const float* wbase = lds_w2[wave];

    // cross-row pipeline: h1c holds row `it`'s ELUs, refilled with row it+1
    const int off0 = (rowBase + lane) * NF + f;
    float h1c[H1];
    {
        const float xv = x[off0];             // row 0
        #pragma unroll
        for (int h = 0; h < H1; ++h)
            h1c[h] = elu_f(fmaf(xv, w1v[h], s_b1[h]));
    }
    float xn  = x[off0 + 64 * NF];            // row 1 (ITERS >= 2)
    int off = off0;

    #pragma unroll 1
    for (int it = 0; it < ITERS; ++it) {
        // prefetch x for row it+2
        const int off2 = off + 2 * 64 * NF;
        const float xnn = x[(it + 2 < ITERS) ? off2 : off];

        float acc[H2];
        #pragma unroll
        for (int k = 0; k < H2; ++k) acc[k] = b2v[k];

        // ---- W2 rows 0..7: SGPR path; consume h1c (row it), refill row it+1
        #pragma unroll
        for (int h = 0; h < 8; ++h) {
            const float hc = h1c[h];
            h1c[h] = elu_f(fmaf(xn, w1v[h], s_b1[h]));
            #pragma unroll
            for (int k = 0; k < H2; ++k)
                acc[k] = fmaf(hc, s_w2[h * H2 + k], acc[k]);
        }

        // ---- W2 rows 8..15: LDS broadcast path ----
        int dsoff = 0;                        // block LICM hoisting
        asm volatile("" : "+v"(dsoff));
        const float4* wp = reinterpret_cast<const float4*>(wbase + dsoff);
        #pragma unroll
        for (int h = 0; h < 8; ++h) {
            const float4 wlo = wp[2 * h];
            const float4 whi = wp[2 * h + 1];
            const float hc = h1c[8 + h];
            h1c[8 + h] = elu_f(fmaf(xn, w1v[8 + h], s_b1[8 + h]));
            acc[0] = fmaf(hc, wlo.x, acc[0]);
            acc[1] = fmaf(hc, wlo.y, acc[1]);
            acc[2] = fmaf(hc, wlo.z, acc[2]);
            acc[3] = fmaf(hc, wlo.w, acc[3]);
            acc[4] = fmaf(hc, whi.x, acc[4]);
            acc[5] = fmaf(hc, whi.y, acc[5]);
            acc[6] = fmaf(hc, whi.z, acc[6]);
            acc[7] = fmaf(hc, whi.w, acc[7]);
        }

        float z = s_b3;
        #pragma unroll
        for (int k = 0; k < H2; ++k)
            z = fmaf(elu_f(acc[k]), s_w3[k], z);

        z_out[off] = z;                       // row it
        off += 64 * NF; xn = xnn;
    }
}

// Memory-bound epilogue: w = softplus(theta); y[row] = dot(z[row,:], w) + bias.
#define NT2 256
#define ROWS2 64
__global__ __launch_bounds__(NT2, 4)
void y_kernel(const float* __restrict__ z, const float* __restrict__ theta,
              const float* __restrict__ bias, float* __restrict__ y_out,
              float* __restrict__ w_out) {
    __shared__ __align__(16) float wls[NF];
    const int tid = threadIdx.x;
    {
        const float th = theta[tid];
        const float w  = logf(1.0f + __expf(th));
        wls[tid] = w;
        if (blockIdx.x == 0) w_out[tid] = w;
    }
    __syncthreads();
    const int wave = tid >> 6, lane = tid & 63;
    const float4 w4 = reinterpret_cast<const float4*>(wls)[lane];
    const float biasv = bias[0];
    #pragma unroll 1
    for (int r = 0; r < ROWS2 / 4; ++r) {          // 16 rows per wave
        const int row = blockIdx.x * ROWS2 + wave * (ROWS2 / 4) + r;
        const float4 zv = reinterpret_cast<const float4*>(z + row * NF)[lane];
        float s = zv.x * w4.x + zv.y * w4.y + zv.z * w4.z + zv.w * w4.w;
        #pragma unroll
        for (int o = 16; o > 0; o >>= 1) s += __shfl_down(s, o, 32);
        s += __shfl_down(s, 32, 64);
        if (lane == 0) y_out[row] = s + biasv;
    }
}

extern "C" void kernel_launch(void* const* d_in, const int* in_sizes, int n_in,
                              void* d_out, int out_size, void* d_ws, size_t ws_size,
                              hipStream_t stream) {
    const float* x     = (const float*)d_in[0];
    const float* W1    = (const float*)d_in[1];
    const float* b1    = (const float*)d_in[2];
    const float* W2    = (const float*)d_in[3];
    const float* b2    = (const float*)d_in[4];
    const float* W3    = (const float*)d_in[5];
    const float* b3    = (const float*)d_in[6];
    const float* theta = (const float*)d_in[7];
    const float* bias  = (const float*)d_in[8];

    float* y_out = (float*)d_out;                  // [32768]
    float* w_out = y_out + NB;                     // [256]
    float* z_out = w_out + NF;                     // [32768*256]

    dim3 grid1(NB / ROWS_PER_BLOCK, NF / FPB);     // 32 x 64
    z_kernel<<<grid1, NT, 0, stream>>>(x, W1, b1, W2, b2, W3, b3, z_out);
    y_kernel<<<NB / ROWS2, NT2, 0, stream>>>(z_out, theta, bias, y_out, w_out);
}